// Round 13
// baseline (162.173 us; speedup 1.0000x reference)
//
#include <hip/hip_runtime.h>
#include <math.h>
#include <stdint.h>

#define B 8
#define C 64
#define H 256
#define W 256
#define NPLANE 16            // 2 inputs x 8 batches
#define PSZ (H * W)          // 65536

// workspace layout
#define OFF_WC    256                        // 2*64*9 f64 = 9216 B
#define OFF_BIAS  9728                       // 2 f64
#define OFF_PART  16384                      // 16 planes * 4 quarters * PSZ f64 = 32 MiB

// ---------------------------------------------------------------------------
// prep: fold pointwise weight into depthwise taps (f64), fold biases.
// ---------------------------------------------------------------------------
__global__ void prep_kernel(const float* __restrict__ dw_w0, const float* __restrict__ dw_b0,
                            const float* __restrict__ pw_w0, const float* __restrict__ pw_b0,
                            const float* __restrict__ dw_w1, const float* __restrict__ dw_b1,
                            const float* __restrict__ pw_w1, const float* __restrict__ pw_b1,
                            double* __restrict__ wc, double* __restrict__ bias)
{
    int t = threadIdx.x;            // 0..127
    int which = t >> 6, c = t & 63;
    const float* dw = which ? dw_w1 : dw_w0;
    const float* pw = which ? pw_w1 : pw_w0;
    double p = (double)pw[c];
    #pragma unroll
    for (int k = 0; k < 9; ++k)
        wc[(which * 64 + c) * 9 + k] = p * (double)dw[c * 9 + k];
    if (c == 0) {
        const float* dwb = which ? dw_b1 : dw_b0;
        const float* pwb = which ? pw_b1 : pw_b0;
        double acc = (double)pwb[0];
        for (int cc = 0; cc < 64; ++cc) acc += (double)pw[cc] * (double)dwb[cc];
        bias[which] = acc;
    }
}

// ---------------------------------------------------------------------------
// 16-channel partial accumulation; plain loads (6 rows batched, no deps
// between them), shuffles for the W-halo, f64 accumulate.
// JLO/JHI skip invalid rows at image top/bottom (zero padding).
// ---------------------------------------------------------------------------
template<int JLO, int JHI>
__device__ __forceinline__ void accum_q(
    const float* __restrict__ xb,   // plane base + cbase*PSZ + lane*4
    const double* __restrict__ w9,  // folded weights for channel cbase (uniform)
    const int gy[6], int lane, double acc[4][4])
{
    #pragma unroll 1
    for (int cc = 0; cc < 16; ++cc) {
        const float* xc = xb + (size_t)cc * PSZ;
        float4 r0 = *(const float4*)(xc + gy[0]);
        float4 r1 = *(const float4*)(xc + gy[1]);
        float4 r2 = *(const float4*)(xc + gy[2]);
        float4 r3 = *(const float4*)(xc + gy[3]);
        float4 r4 = *(const float4*)(xc + gy[4]);
        float4 r5 = *(const float4*)(xc + gy[5]);

        double wl[9];
        #pragma unroll
        for (int t = 0; t < 9; ++t) wl[t] = w9[cc * 9 + t];   // uniform -> s_load

        const float4 rr[6] = {r0, r1, r2, r3, r4, r5};
        #pragma unroll
        for (int j = 0; j < 6; ++j) {
            if (j < JLO || j > JHI) continue;
            float lf = __shfl_up(rr[j].w, 1);
            float rf = __shfl_down(rr[j].x, 1);
            if (lane == 0)  lf = 0.0f;
            if (lane == 63) rf = 0.0f;
            double dd[6] = {(double)lf, (double)rr[j].x, (double)rr[j].y,
                            (double)rr[j].z, (double)rr[j].w, (double)rf};
            #pragma unroll
            for (int i = 0; i < 3; ++i) {
                const int o = j - i;                 // output row
                if (o >= 0 && o < 4) {
                    double wa = wl[3 * i], wb = wl[3 * i + 1], wcv = wl[3 * i + 2];
                    #pragma unroll
                    for (int k = 0; k < 4; ++k)
                        acc[o][k] += wa * dd[k] + wb * dd[k + 1] + wcv * dd[k + 2];
                }
            }
        }
    }
}

// ---------------------------------------------------------------------------
// score partials: ONE WAVE per block, no LDS, no barriers — structurally
// identical to the (fast) select kernel. 4096 blocks = (16 planes x 64 bands
// x 4 channel-quarters); all 16 waves/CU resident in one generation.
// Partial q covers channels [16q,16q+16); summed q-ascending in select
// (same grouping as the previous passing 4-wave reduction).
// ---------------------------------------------------------------------------
__global__ __launch_bounds__(64) void score_part_kernel(
    const float* __restrict__ x0, const float* __restrict__ x1,
    const double* __restrict__ wc, double* __restrict__ part)
{
    // XCD-bijective swizzle (4096 = 8*512): adjacent tasks share an XCD.
    const int n    = blockIdx.x;
    const int task = (n & 7) * 512 + (n >> 3);
    const int plane = task >> 8;          // 0..15
    const int band  = (task >> 2) & 63;   // 0..63
    const int q     = task & 3;           // channel quarter
    const int which = plane >> 3;
    const int b     = plane & 7;
    const int y0    = band * 4;

    const int lane = threadIdx.x;

    const float*  xb = (which ? x1 : x0) + (size_t)b * C * PSZ
                     + (size_t)(q * 16) * PSZ + lane * 4;
    const double* w9 = wc + which * (C * 9) + (q * 16) * 9;

    int gy[6];
    #pragma unroll
    for (int j = 0; j < 6; ++j) {
        int r = y0 - 1 + j;
        r = r < 0 ? 0 : (r > H - 1 ? H - 1 : r);   // clamped; edge rows skipped
        gy[j] = r * W;
    }

    double acc[4][4] = {};   // [out-row][px]

    if (band == 0)       accum_q<1, 5>(xb, w9, gy, lane, acc);
    else if (band == 63) accum_q<0, 4>(xb, w9, gy, lane, acc);
    else                 accum_q<0, 5>(xb, w9, gy, lane, acc);

    double* pp = part + ((size_t)plane * 4 + q) * PSZ + (size_t)y0 * W + lane * 4;
    #pragma unroll
    for (int o = 0; o < 4; ++o) {
        double2* row = (double2*)(pp + o * W);
        row[0] = make_double2(acc[o][0], acc[o][1]);
        row[1] = make_double2(acc[o][2], acc[o][3]);
    }
}

// ---------------------------------------------------------------------------
// Selection + score finalize. block = one (b,y) row; 256 threads =
// 64 float4-cols x 4 channel groups. Sums the 4 partials (fixed order) +
// bias, sigmoid, then selects; f64 so the argmax matches the f64 reference.
// ---------------------------------------------------------------------------
__global__ __launch_bounds__(256) void select_kernel(
    const float*  __restrict__ x0,
    const float*  __restrict__ x1,
    const double* __restrict__ part,
    const double* __restrict__ bias,
    float* __restrict__ out,
    unsigned int* __restrict__ count1)
{
    const int by = blockIdx.x;        // 0 .. B*H-1
    const int b  = by >> 8;
    const int y  = by & (H - 1);
    const int tx = threadIdx.x & 63;  // float4 column
    const int tc = threadIdx.x >> 6;  // 0..3 channel group

    // finalize f for this thread's 4 pixels (both inputs)
    const size_t rowoff = (size_t)y * W + (size_t)tx * 4;
    double s0[4] = {}, s1[4] = {};
    #pragma unroll
    for (int q = 0; q < 4; ++q) {     // fixed q-ascending order (deterministic)
        const double* p0 = part + ((size_t)b * 4 + q) * PSZ + rowoff;
        const double* p1 = part + ((size_t)(8 + b) * 4 + q) * PSZ + rowoff;
        #pragma unroll
        for (int j = 0; j < 4; ++j) { s0[j] += p0[j]; s1[j] += p1[j]; }
    }
    const double bv0 = bias[0], bv1 = bias[1];
    double g0[4], g1[4];
    #pragma unroll
    for (int j = 0; j < 4; ++j) {
        g0[j] = 1.0 + 1.0 / (1.0 + exp(-(s0[j] + bv0)));
        g1[j] = 1.0 + 1.0 / (1.0 + exp(-(s1[j] + bv1)));
    }

    const size_t rowbase = (size_t)b * C * H * W + rowoff;

    unsigned int cnt = 0;
    for (int ci = tc; ci < C; ci += 4) {
        size_t off = rowbase + (size_t)ci * H * W;
        float4 a  = *(const float4*)(x0 + off);
        float4 bb = *(const float4*)(x1 + off);
        float4 r;
        { double w0=(double)a.x*g0[0], w1=(double)bb.x*g1[0]; bool s1_=(w1>w0); cnt+=s1_; r.x=s1_?bb.x:a.x; }
        { double w0=(double)a.y*g0[1], w1=(double)bb.y*g1[1]; bool s1_=(w1>w0); cnt+=s1_; r.y=s1_?bb.y:a.y; }
        { double w0=(double)a.z*g0[2], w1=(double)bb.z*g1[2]; bool s1_=(w1>w0); cnt+=s1_; r.z=s1_?bb.z:a.z; }
        { double w0=(double)a.w*g0[3], w1=(double)bb.w*g1[3]; bool s1_=(w1>w0); cnt+=s1_; r.w=s1_?bb.w:a.w; }
        *(float4*)(out + off) = r;
    }

    __shared__ unsigned int blk;
    if (threadIdx.x == 0) blk = 0;
    __syncthreads();
    atomicAdd(&blk, cnt);
    __syncthreads();
    if (threadIdx.x == 0) atomicAdd(count1, blk);
}

__global__ void finalize_kernel(const unsigned int* __restrict__ count1,
                                float* __restrict__ out_p)
{
    const double N = (double)B * C * H * W;
    double c1 = (double)(*count1);
    out_p[0] = (float)((N - c1) / N);
    out_p[1] = (float)(c1 / N);
}

extern "C" void kernel_launch(void* const* d_in, const int* in_sizes, int n_in,
                              void* d_out, int out_size, void* d_ws, size_t ws_size,
                              hipStream_t stream) {
    const float* x0    = (const float*)d_in[0];
    const float* x1    = (const float*)d_in[1];
    const float* dw_w0 = (const float*)d_in[2];
    const float* dw_b0 = (const float*)d_in[3];
    const float* pw_w0 = (const float*)d_in[4];
    const float* pw_b0 = (const float*)d_in[5];
    const float* dw_w1 = (const float*)d_in[6];
    const float* dw_b1 = (const float*)d_in[7];
    const float* pw_w1 = (const float*)d_in[8];
    const float* pw_b1 = (const float*)d_in[9];
    float* out = (float*)d_out;

    unsigned int* cnt  = (unsigned int*)d_ws;
    double*       wc   = (double*)((char*)d_ws + OFF_WC);
    double*       bias = (double*)((char*)d_ws + OFF_BIAS);
    double*       part = (double*)((char*)d_ws + OFF_PART);

    (void)hipMemsetAsync(d_ws, 0, 256, stream);

    prep_kernel<<<1, 128, 0, stream>>>(dw_w0, dw_b0, pw_w0, pw_b0,
                                       dw_w1, dw_b1, pw_w1, pw_b1, wc, bias);

    score_part_kernel<<<NPLANE * 64 * 4, 64, 0, stream>>>(x0, x1, wc, part);

    select_kernel<<<B * H, 256, 0, stream>>>(x0, x1, part, bias, out, cnt);

    finalize_kernel<<<1, 1, 0, stream>>>(cnt, out + (size_t)B * C * H * W);
}

// Round 14
// 159.460 us; speedup vs baseline: 1.0170x; 1.0170x over previous
//
#include <hip/hip_runtime.h>
#include <math.h>
#include <stdint.h>

#define B 8
#define C 64
#define H 256
#define W 256
#define NPLANE 16            // 2 inputs x 8 batches
#define PSZ (H * W)          // 65536

// workspace layout
#define OFF_WC    256                        // 2*64*9 f64 = 9216 B
#define OFF_BIAS  9728                       // 2 f64
#define OFF_PART  16384                      // 16 planes * 4 quarters * PSZ f64 = 32 MiB

// ---------------------------------------------------------------------------
// prep: fold pointwise weight into depthwise taps (f64), fold biases.
// ---------------------------------------------------------------------------
__global__ void prep_kernel(const float* __restrict__ dw_w0, const float* __restrict__ dw_b0,
                            const float* __restrict__ pw_w0, const float* __restrict__ pw_b0,
                            const float* __restrict__ dw_w1, const float* __restrict__ dw_b1,
                            const float* __restrict__ pw_w1, const float* __restrict__ pw_b1,
                            double* __restrict__ wc, double* __restrict__ bias)
{
    int t = threadIdx.x;            // 0..127
    int which = t >> 6, c = t & 63;
    const float* dw = which ? dw_w1 : dw_w0;
    const float* pw = which ? pw_w1 : pw_w0;
    double p = (double)pw[c];
    #pragma unroll
    for (int k = 0; k < 9; ++k)
        wc[(which * 64 + c) * 9 + k] = p * (double)dw[c * 9 + k];
    if (c == 0) {
        const float* dwb = which ? dw_b1 : dw_b0;
        const float* pwb = which ? pw_b1 : pw_b0;
        double acc = (double)pwb[0];
        for (int cc = 0; cc < 64; ++cc) acc += (double)pw[cc] * (double)dwb[cc];
        bias[which] = acc;
    }
}

// ---------------------------------------------------------------------------
// 16-channel partial accumulation for a 2-ROW band; 4 independent row loads
// per channel (small live set -> stays batched), shuffles for the W-halo,
// f64 accumulate. JLO/JHI skip invalid rows at image top/bottom (zero pad).
// ---------------------------------------------------------------------------
template<int JLO, int JHI>
__device__ __forceinline__ void accum_q(
    const float* __restrict__ xb,   // plane base + cbase*PSZ + lane*4
    const double* __restrict__ w9,  // folded weights for channel cbase (uniform)
    const int gy[4], int lane, double acc[2][4])
{
    #pragma unroll 1
    for (int cc = 0; cc < 16; ++cc) {
        const float* xc = xb + (size_t)cc * PSZ;
        float4 r0 = *(const float4*)(xc + gy[0]);
        float4 r1 = *(const float4*)(xc + gy[1]);
        float4 r2 = *(const float4*)(xc + gy[2]);
        float4 r3 = *(const float4*)(xc + gy[3]);

        double wl[9];
        #pragma unroll
        for (int t = 0; t < 9; ++t) wl[t] = w9[cc * 9 + t];   // uniform -> s_load

        const float4 rr[4] = {r0, r1, r2, r3};
        #pragma unroll
        for (int j = 0; j < 4; ++j) {
            if (j < JLO || j > JHI) continue;
            float lf = __shfl_up(rr[j].w, 1);
            float rf = __shfl_down(rr[j].x, 1);
            if (lane == 0)  lf = 0.0f;
            if (lane == 63) rf = 0.0f;
            double dd[6] = {(double)lf, (double)rr[j].x, (double)rr[j].y,
                            (double)rr[j].z, (double)rr[j].w, (double)rf};
            #pragma unroll
            for (int i = 0; i < 3; ++i) {
                const int o = j - i;                 // output row (0..1)
                if (o >= 0 && o < 2) {
                    double wa = wl[3 * i], wb = wl[3 * i + 1], wcv = wl[3 * i + 2];
                    #pragma unroll
                    for (int k = 0; k < 4; ++k)
                        acc[o][k] += wa * dd[k] + wb * dd[k + 1] + wcv * dd[k + 2];
                }
            }
        }
    }
}

// ---------------------------------------------------------------------------
// score partials: ONE WAVE per block, no LDS, no barriers. 8192 blocks =
// (16 planes x 128 two-row bands x 4 channel-quarters) -> 32 waves/CU
// capacity; occupancy (not per-wave MLP) supplies outstanding requests.
// Partial q covers channels [16q,16q+16); summed q-ascending in select.
// ---------------------------------------------------------------------------
__global__ __launch_bounds__(64) void score_part_kernel(
    const float* __restrict__ x0, const float* __restrict__ x1,
    const double* __restrict__ wc, double* __restrict__ part)
{
    // XCD-bijective swizzle (8192 = 8*1024): adjacent tasks share an XCD.
    const int n    = blockIdx.x;
    const int task = (n & 7) * 1024 + (n >> 3);
    const int plane = task >> 9;          // 0..15   (512 tasks per plane)
    const int band  = (task >> 2) & 127;  // 0..127
    const int q     = task & 3;           // channel quarter
    const int which = plane >> 3;
    const int b     = plane & 7;
    const int y0    = band * 2;

    const int lane = threadIdx.x;

    const float*  xb = (which ? x1 : x0) + (size_t)b * C * PSZ
                     + (size_t)(q * 16) * PSZ + lane * 4;
    const double* w9 = wc + which * (C * 9) + (q * 16) * 9;

    int gy[4];
    #pragma unroll
    for (int j = 0; j < 4; ++j) {
        int r = y0 - 1 + j;
        r = r < 0 ? 0 : (r > H - 1 ? H - 1 : r);   // clamped; edge rows skipped
        gy[j] = r * W;
    }

    double acc[2][4] = {};   // [out-row][px]

    if (band == 0)        accum_q<1, 3>(xb, w9, gy, lane, acc);
    else if (band == 127) accum_q<0, 2>(xb, w9, gy, lane, acc);
    else                  accum_q<0, 3>(xb, w9, gy, lane, acc);

    double* pp = part + ((size_t)plane * 4 + q) * PSZ + (size_t)y0 * W + lane * 4;
    #pragma unroll
    for (int o = 0; o < 2; ++o) {
        double2* row = (double2*)(pp + o * W);
        row[0] = make_double2(acc[o][0], acc[o][1]);
        row[1] = make_double2(acc[o][2], acc[o][3]);
    }
}

// ---------------------------------------------------------------------------
// Selection + score finalize. block = one (b,y) row; 256 threads =
// 64 float4-cols x 4 channel groups. Sums the 4 partials (fixed order) +
// bias, sigmoid, then selects; f64 so the argmax matches the f64 reference.
// ---------------------------------------------------------------------------
__global__ __launch_bounds__(256) void select_kernel(
    const float*  __restrict__ x0,
    const float*  __restrict__ x1,
    const double* __restrict__ part,
    const double* __restrict__ bias,
    float* __restrict__ out,
    unsigned int* __restrict__ count1)
{
    const int by = blockIdx.x;        // 0 .. B*H-1
    const int b  = by >> 8;
    const int y  = by & (H - 1);
    const int tx = threadIdx.x & 63;  // float4 column
    const int tc = threadIdx.x >> 6;  // 0..3 channel group

    // finalize f for this thread's 4 pixels (both inputs)
    const size_t rowoff = (size_t)y * W + (size_t)tx * 4;
    double s0[4] = {}, s1[4] = {};
    #pragma unroll
    for (int q = 0; q < 4; ++q) {     // fixed q-ascending order (deterministic)
        const double* p0 = part + ((size_t)b * 4 + q) * PSZ + rowoff;
        const double* p1 = part + ((size_t)(8 + b) * 4 + q) * PSZ + rowoff;
        #pragma unroll
        for (int j = 0; j < 4; ++j) { s0[j] += p0[j]; s1[j] += p1[j]; }
    }
    const double bv0 = bias[0], bv1 = bias[1];
    double g0[4], g1[4];
    #pragma unroll
    for (int j = 0; j < 4; ++j) {
        g0[j] = 1.0 + 1.0 / (1.0 + exp(-(s0[j] + bv0)));
        g1[j] = 1.0 + 1.0 / (1.0 + exp(-(s1[j] + bv1)));
    }

    const size_t rowbase = (size_t)b * C * H * W + rowoff;

    unsigned int cnt = 0;
    for (int ci = tc; ci < C; ci += 4) {
        size_t off = rowbase + (size_t)ci * H * W;
        float4 a  = *(const float4*)(x0 + off);
        float4 bb = *(const float4*)(x1 + off);
        float4 r;
        { double w0=(double)a.x*g0[0], w1=(double)bb.x*g1[0]; bool s1_=(w1>w0); cnt+=s1_; r.x=s1_?bb.x:a.x; }
        { double w0=(double)a.y*g0[1], w1=(double)bb.y*g1[1]; bool s1_=(w1>w0); cnt+=s1_; r.y=s1_?bb.y:a.y; }
        { double w0=(double)a.z*g0[2], w1=(double)bb.z*g1[2]; bool s1_=(w1>w0); cnt+=s1_; r.z=s1_?bb.z:a.z; }
        { double w0=(double)a.w*g0[3], w1=(double)bb.w*g1[3]; bool s1_=(w1>w0); cnt+=s1_; r.w=s1_?bb.w:a.w; }
        *(float4*)(out + off) = r;
    }

    __shared__ unsigned int blk;
    if (threadIdx.x == 0) blk = 0;
    __syncthreads();
    atomicAdd(&blk, cnt);
    __syncthreads();
    if (threadIdx.x == 0) atomicAdd(count1, blk);
}

__global__ void finalize_kernel(const unsigned int* __restrict__ count1,
                                float* __restrict__ out_p)
{
    const double N = (double)B * C * H * W;
    double c1 = (double)(*count1);
    out_p[0] = (float)((N - c1) / N);
    out_p[1] = (float)(c1 / N);
}

extern "C" void kernel_launch(void* const* d_in, const int* in_sizes, int n_in,
                              void* d_out, int out_size, void* d_ws, size_t ws_size,
                              hipStream_t stream) {
    const float* x0    = (const float*)d_in[0];
    const float* x1    = (const float*)d_in[1];
    const float* dw_w0 = (const float*)d_in[2];
    const float* dw_b0 = (const float*)d_in[3];
    const float* pw_w0 = (const float*)d_in[4];
    const float* pw_b0 = (const float*)d_in[5];
    const float* dw_w1 = (const float*)d_in[6];
    const float* dw_b1 = (const float*)d_in[7];
    const float* pw_w1 = (const float*)d_in[8];
    const float* pw_b1 = (const float*)d_in[9];
    float* out = (float*)d_out;

    unsigned int* cnt  = (unsigned int*)d_ws;
    double*       wc   = (double*)((char*)d_ws + OFF_WC);
    double*       bias = (double*)((char*)d_ws + OFF_BIAS);
    double*       part = (double*)((char*)d_ws + OFF_PART);

    (void)hipMemsetAsync(d_ws, 0, 256, stream);

    prep_kernel<<<1, 128, 0, stream>>>(dw_w0, dw_b0, pw_w0, pw_b0,
                                       dw_w1, dw_b1, pw_w1, pw_b1, wc, bias);

    score_part_kernel<<<NPLANE * 128 * 4, 64, 0, stream>>>(x0, x1, wc, part);

    select_kernel<<<B * H, 256, 0, stream>>>(x0, x1, part, bias, out, cnt);

    finalize_kernel<<<1, 1, 0, stream>>>(cnt, out + (size_t)B * C * H * W);
}

// Round 15
// 132.997 us; speedup vs baseline: 1.2194x; 1.1990x over previous
//
#include <hip/hip_runtime.h>
#include <math.h>
#include <stdint.h>

#define B 8
#define C 64
#define H 256
#define W 256
#define PSZ (H * W)          // 65536

// workspace layout
#define OFF_WC    256                        // 2*64*9 f64 = 9216 B
#define OFF_BIAS  9728                       // 2 f64

// ---------------------------------------------------------------------------
// prep: fold pointwise weight into depthwise taps (f64), fold biases.
// ---------------------------------------------------------------------------
__global__ void prep_kernel(const float* __restrict__ dw_w0, const float* __restrict__ dw_b0,
                            const float* __restrict__ pw_w0, const float* __restrict__ pw_b0,
                            const float* __restrict__ dw_w1, const float* __restrict__ dw_b1,
                            const float* __restrict__ pw_w1, const float* __restrict__ pw_b1,
                            double* __restrict__ wc, double* __restrict__ bias)
{
    int t = threadIdx.x;            // 0..127
    int which = t >> 6, c = t & 63;
    const float* dw = which ? dw_w1 : dw_w0;
    const float* pw = which ? pw_w1 : pw_w0;
    double p = (double)pw[c];
    #pragma unroll
    for (int k = 0; k < 9; ++k)
        wc[(which * 64 + c) * 9 + k] = p * (double)dw[c * 9 + k];
    if (c == 0) {
        const float* dwb = which ? dw_b1 : dw_b0;
        const float* pwb = which ? pw_b1 : pw_b0;
        double acc = (double)pwb[0];
        for (int cc = 0; cc < 64; ++cc) acc += (double)pw[cc] * (double)dwb[cc];
        bias[which] = acc;
    }
}

// ---------------------------------------------------------------------------
// 16-channel partial accumulation for a 2-row band (identical math/order to
// the passing round-14 kernel -> bit-identical f). 4 independent row loads
// per channel, shuffles for the W-halo, f64 accumulate.
// JLO/JHI skip invalid rows at image top/bottom (zero padding).
// ---------------------------------------------------------------------------
template<int JLO, int JHI>
__device__ __forceinline__ void accum_q(
    const float* __restrict__ xb,   // plane base + chunk*16*PSZ + lane*4
    const double* __restrict__ w9,  // folded weights for this chunk (uniform)
    const int gy[4], int lane, double acc[2][4])
{
    #pragma unroll 1
    for (int cc = 0; cc < 16; ++cc) {
        const float* xc = xb + (size_t)cc * PSZ;
        float4 r0 = *(const float4*)(xc + gy[0]);
        float4 r1 = *(const float4*)(xc + gy[1]);
        float4 r2 = *(const float4*)(xc + gy[2]);
        float4 r3 = *(const float4*)(xc + gy[3]);

        double wl[9];
        #pragma unroll
        for (int t = 0; t < 9; ++t) wl[t] = w9[cc * 9 + t];   // uniform -> s_load

        const float4 rr[4] = {r0, r1, r2, r3};
        #pragma unroll
        for (int j = 0; j < 4; ++j) {
            if (j < JLO || j > JHI) continue;
            float lf = __shfl_up(rr[j].w, 1);
            float rf = __shfl_down(rr[j].x, 1);
            if (lane == 0)  lf = 0.0f;
            if (lane == 63) rf = 0.0f;
            double dd[6] = {(double)lf, (double)rr[j].x, (double)rr[j].y,
                            (double)rr[j].z, (double)rr[j].w, (double)rf};
            #pragma unroll
            for (int i = 0; i < 3; ++i) {
                const int o = j - i;                 // output row (0..1)
                if (o >= 0 && o < 2) {
                    double wa = wl[3 * i], wb = wl[3 * i + 1], wcv = wl[3 * i + 2];
                    #pragma unroll
                    for (int k = 0; k < 4; ++k)
                        acc[o][k] += wa * dd[k] + wb * dd[k + 1] + wcv * dd[k + 2];
                }
            }
        }
    }
}

// ---------------------------------------------------------------------------
// FUSED kernel: score (both inputs) + sigmoid + select + count for one
// (batch, 2-row band). 512 threads = 8 waves = 2 inputs x 4 chunks x 16 ch.
// The select phase re-reads x rows the block just fetched (L2-hot) and
// writes out directly — no partial planes, no second cold pass over x.
// f64 end-to-end; summation order identical to the passing round-14 split
// (chunk-ascending, then bias) -> bit-identical f -> absmax 0.
// ---------------------------------------------------------------------------
__global__ __launch_bounds__(512) void fused_kernel(
    const float* __restrict__ x0, const float* __restrict__ x1,
    const double* __restrict__ wc, const double* __restrict__ bias,
    float* __restrict__ out, unsigned int* __restrict__ count1)
{
    __shared__ double sred[2][4][2][4][64];   // 32 KiB [which][chunk][row][k][lane]; reused for f
    __shared__ unsigned int scnt;

    // XCD-bijective swizzle (1024 = 8*128): adjacent bands share an XCD.
    const int n    = blockIdx.x;
    const int task = (n & 7) * 128 + (n >> 3);
    const int b    = task >> 7;          // 0..7
    const int band = task & 127;         // 0..127
    const int y0   = band * 2;

    const int tid   = threadIdx.x;
    const int w     = tid >> 6;          // wave 0..7
    const int lane  = tid & 63;
    const int which = w >> 2;            // input 0/1
    const int chunk = w & 3;             // channel quarter

    if (tid == 0) scnt = 0;

    const float* xin = which ? x1 : x0;
    const float* xb  = xin + (size_t)b * C * PSZ + (size_t)(chunk * 16) * PSZ + lane * 4;
    const double* w9 = wc + which * (C * 9) + (chunk * 16) * 9;

    int gy[4];
    #pragma unroll
    for (int j = 0; j < 4; ++j) {
        int r = y0 - 1 + j;
        r = r < 0 ? 0 : (r > H - 1 ? H - 1 : r);   // clamped; edge rows skipped
        gy[j] = r * W;
    }

    double acc[2][4] = {};   // [out-row][px]

    if (band == 0)        accum_q<1, 3>(xb, w9, gy, lane, acc);
    else if (band == 127) accum_q<0, 2>(xb, w9, gy, lane, acc);
    else                  accum_q<0, 3>(xb, w9, gy, lane, acc);

    #pragma unroll
    for (int o = 0; o < 2; ++o)
        #pragma unroll
        for (int k = 0; k < 4; ++k)
            sred[which][chunk][o][k][lane] = acc[o][k];
    __syncthreads();

    // f for 1024 (which,row,px) cells: 2 per thread, into registers first.
    double fv0, fv1;
    {
        int idx = tid;                       // it = 0
        int wh = idx >> 9, row = (idx >> 8) & 1, px = idx & 255;
        int k = px & 3, l = px >> 2;
        double s = sred[wh][0][row][k][l] + sred[wh][1][row][k][l]
                 + sred[wh][2][row][k][l] + sred[wh][3][row][k][l] + bias[wh];
        fv0 = 1.0 + 1.0 / (1.0 + exp(-s));
    }
    {
        int idx = 512 + tid;                 // it = 1
        int wh = idx >> 9, row = (idx >> 8) & 1, px = idx & 255;
        int k = px & 3, l = px >> 2;
        double s = sred[wh][0][row][k][l] + sred[wh][1][row][k][l]
                 + sred[wh][2][row][k][l] + sred[wh][3][row][k][l] + bias[wh];
        fv1 = 1.0 + 1.0 / (1.0 + exp(-s));
    }
    __syncthreads();                         // all sred reads done

    double* sf = &sred[0][0][0][0][0];       // reuse as flat [which*512 + row*256 + px]
    sf[tid] = fv0;
    sf[512 + tid] = fv1;
    __syncthreads();

    // ---- select phase: 2 rows x 64 ch, reading L2-hot x, writing out ----
    const int tx = tid & 63;                 // float4 column
    const int tc = tid >> 6;                 // 0..7 channel group

    double g0[2][4], g1[2][4];               // [row][j]
    #pragma unroll
    for (int row = 0; row < 2; ++row)
        #pragma unroll
        for (int j = 0; j < 4; ++j) {
            g0[row][j] = sf[row * 256 + tx * 4 + j];
            g1[row][j] = sf[512 + row * 256 + tx * 4 + j];
        }

    unsigned int cnt = 0;
    const size_t base = (size_t)b * C * PSZ + (size_t)y0 * W + (size_t)tx * 4;
    #pragma unroll 1
    for (int ci = tc; ci < C; ci += 8) {
        #pragma unroll
        for (int row = 0; row < 2; ++row) {
            size_t off = base + (size_t)ci * PSZ + (size_t)row * W;
            float4 a  = *(const float4*)(x0 + off);
            float4 bb = *(const float4*)(x1 + off);
            float4 r;
            { double v0=(double)a.x*g0[row][0], v1=(double)bb.x*g1[row][0]; bool s1=(v1>v0); cnt+=s1; r.x=s1?bb.x:a.x; }
            { double v0=(double)a.y*g0[row][1], v1=(double)bb.y*g1[row][1]; bool s1=(v1>v0); cnt+=s1; r.y=s1?bb.y:a.y; }
            { double v0=(double)a.z*g0[row][2], v1=(double)bb.z*g1[row][2]; bool s1=(v1>v0); cnt+=s1; r.z=s1?bb.z:a.z; }
            { double v0=(double)a.w*g0[row][3], v1=(double)bb.w*g1[row][3]; bool s1=(v1>v0); cnt+=s1; r.w=s1?bb.w:a.w; }
            *(float4*)(out + off) = r;
        }
    }

    atomicAdd(&scnt, cnt);
    __syncthreads();
    if (tid == 0) atomicAdd(count1, scnt);
}

__global__ void finalize_kernel(const unsigned int* __restrict__ count1,
                                float* __restrict__ out_p)
{
    const double N = (double)B * C * H * W;
    double c1 = (double)(*count1);
    out_p[0] = (float)((N - c1) / N);
    out_p[1] = (float)(c1 / N);
}

extern "C" void kernel_launch(void* const* d_in, const int* in_sizes, int n_in,
                              void* d_out, int out_size, void* d_ws, size_t ws_size,
                              hipStream_t stream) {
    const float* x0    = (const float*)d_in[0];
    const float* x1    = (const float*)d_in[1];
    const float* dw_w0 = (const float*)d_in[2];
    const float* dw_b0 = (const float*)d_in[3];
    const float* pw_w0 = (const float*)d_in[4];
    const float* pw_b0 = (const float*)d_in[5];
    const float* dw_w1 = (const float*)d_in[6];
    const float* dw_b1 = (const float*)d_in[7];
    const float* pw_w1 = (const float*)d_in[8];
    const float* pw_b1 = (const float*)d_in[9];
    float* out = (float*)d_out;

    unsigned int* cnt  = (unsigned int*)d_ws;
    double*       wc   = (double*)((char*)d_ws + OFF_WC);
    double*       bias = (double*)((char*)d_ws + OFF_BIAS);

    (void)hipMemsetAsync(d_ws, 0, 256, stream);

    prep_kernel<<<1, 128, 0, stream>>>(dw_w0, dw_b0, pw_w0, pw_b0,
                                       dw_w1, dw_b1, pw_w1, pw_b1, wc, bias);

    fused_kernel<<<B * (H / 2), 512, 0, stream>>>(x0, x1, wc, bias, out, cnt);

    finalize_kernel<<<1, 1, 0, stream>>>(cnt, out + (size_t)B * C * H * W);
}

// Round 16
// 129.307 us; speedup vs baseline: 1.2542x; 1.0285x over previous
//
#include <hip/hip_runtime.h>
#include <math.h>
#include <stdint.h>

#define B 8
#define C 64
#define H 256
#define W 256
#define PSZ (H * W)          // 65536

// workspace layout
#define OFF_WC    256                        // 2*64*9 f64 = 9216 B
#define OFF_BIAS  9728                       // 2 f64

// ---------------------------------------------------------------------------
// prep: fold pointwise weight into depthwise taps (f64), fold biases.
// ---------------------------------------------------------------------------
__global__ void prep_kernel(const float* __restrict__ dw_w0, const float* __restrict__ dw_b0,
                            const float* __restrict__ pw_w0, const float* __restrict__ pw_b0,
                            const float* __restrict__ dw_w1, const float* __restrict__ dw_b1,
                            const float* __restrict__ pw_w1, const float* __restrict__ pw_b1,
                            double* __restrict__ wc, double* __restrict__ bias)
{
    int t = threadIdx.x;            // 0..127
    int which = t >> 6, c = t & 63;
    const float* dw = which ? dw_w1 : dw_w0;
    const float* pw = which ? pw_w1 : pw_w0;
    double p = (double)pw[c];
    #pragma unroll
    for (int k = 0; k < 9; ++k)
        wc[(which * 64 + c) * 9 + k] = p * (double)dw[c * 9 + k];
    if (c == 0) {
        const float* dwb = which ? dw_b1 : dw_b0;
        const float* pwb = which ? pw_b1 : pw_b0;
        double acc = (double)pwb[0];
        for (int cc = 0; cc < 64; ++cc) acc += (double)pw[cc] * (double)dwb[cc];
        bias[which] = acc;
    }
}

// ---------------------------------------------------------------------------
// one channel's compute from 4 halo rows (FP order identical to round 15).
// ---------------------------------------------------------------------------
template<int JLO, int JHI>
__device__ __forceinline__ void ch_compute(
    float4 r0, float4 r1, float4 r2, float4 r3,
    const double* __restrict__ wl9,   // 9 folded weights (uniform -> s_load)
    int lane, double acc[2][4])
{
    double wl[9];
    #pragma unroll
    for (int t = 0; t < 9; ++t) wl[t] = wl9[t];

    const float4 rr[4] = {r0, r1, r2, r3};
    #pragma unroll
    for (int j = 0; j < 4; ++j) {
        if (j < JLO || j > JHI) continue;
        float lf = __shfl_up(rr[j].w, 1);
        float rf = __shfl_down(rr[j].x, 1);
        if (lane == 0)  lf = 0.0f;
        if (lane == 63) rf = 0.0f;
        double dd[6] = {(double)lf, (double)rr[j].x, (double)rr[j].y,
                        (double)rr[j].z, (double)rr[j].w, (double)rf};
        #pragma unroll
        for (int i = 0; i < 3; ++i) {
            const int o = j - i;                 // output row (0..1)
            if (o >= 0 && o < 2) {
                double wa = wl[3 * i], wb = wl[3 * i + 1], wcv = wl[3 * i + 2];
                #pragma unroll
                for (int k = 0; k < 4; ++k)
                    acc[o][k] += wa * dd[k] + wb * dd[k + 1] + wcv * dd[k + 2];
            }
        }
    }
}

// ---------------------------------------------------------------------------
// 16-channel accumulation, 2-channel unroll: 8 independent row loads issued
// straight-line, then sched_barrier(0) pins them ABOVE the compute — the
// scheduler cannot sink loads to save registers (the serializer in every
// prior round). Channel cc computed fully before cc+1 -> bit-identical f.
// ---------------------------------------------------------------------------
template<int JLO, int JHI>
__device__ __forceinline__ void accum_q(
    const float* __restrict__ xb,   // plane base + chunk*16*PSZ + lane*4
    const double* __restrict__ w9,  // folded weights for this chunk (uniform)
    const int gy[4], int lane, double acc[2][4])
{
    #pragma unroll 1
    for (int cc = 0; cc < 16; cc += 2) {
        const float* xcA = xb + (size_t)cc * PSZ;
        const float* xcB = xcA + PSZ;
        float4 a0 = *(const float4*)(xcA + gy[0]);
        float4 a1 = *(const float4*)(xcA + gy[1]);
        float4 a2 = *(const float4*)(xcA + gy[2]);
        float4 a3 = *(const float4*)(xcA + gy[3]);
        float4 b0 = *(const float4*)(xcB + gy[0]);
        float4 b1 = *(const float4*)(xcB + gy[1]);
        float4 b2 = *(const float4*)(xcB + gy[2]);
        float4 b3 = *(const float4*)(xcB + gy[3]);
        __builtin_amdgcn_sched_barrier(0);   // loads stay batched above
        ch_compute<JLO, JHI>(a0, a1, a2, a3, w9 + cc * 9, lane, acc);
        ch_compute<JLO, JHI>(b0, b1, b2, b3, w9 + (cc + 1) * 9, lane, acc);
    }
}

// ---------------------------------------------------------------------------
// FUSED kernel: score (both inputs) + sigmoid + select + count for one
// (batch, 2-row band). 512 threads = 8 waves = 2 inputs x 4 chunks x 16 ch.
// f64 end-to-end; summation order identical to rounds 14/15 -> absmax 0.
// ---------------------------------------------------------------------------
__global__ __launch_bounds__(512) void fused_kernel(
    const float* __restrict__ x0, const float* __restrict__ x1,
    const double* __restrict__ wc, const double* __restrict__ bias,
    float* __restrict__ out, unsigned int* __restrict__ count1)
{
    __shared__ double sred[2][4][2][4][64];   // 32 KiB [which][chunk][row][k][lane]; reused for f
    __shared__ unsigned int scnt;

    // XCD-bijective swizzle (1024 = 8*128): adjacent bands share an XCD.
    const int n    = blockIdx.x;
    const int task = (n & 7) * 128 + (n >> 3);
    const int b    = task >> 7;          // 0..7
    const int band = task & 127;         // 0..127
    const int y0   = band * 2;

    const int tid   = threadIdx.x;
    const int w     = tid >> 6;          // wave 0..7
    const int lane  = tid & 63;
    const int which = w >> 2;            // input 0/1
    const int chunk = w & 3;             // channel quarter

    if (tid == 0) scnt = 0;

    const float* xin = which ? x1 : x0;
    const float* xb  = xin + (size_t)b * C * PSZ + (size_t)(chunk * 16) * PSZ + lane * 4;
    const double* w9 = wc + which * (C * 9) + (chunk * 16) * 9;

    int gy[4];
    #pragma unroll
    for (int j = 0; j < 4; ++j) {
        int r = y0 - 1 + j;
        r = r < 0 ? 0 : (r > H - 1 ? H - 1 : r);   // clamped; edge rows skipped
        gy[j] = r * W;
    }

    double acc[2][4] = {};   // [out-row][px]

    if (band == 0)        accum_q<1, 3>(xb, w9, gy, lane, acc);
    else if (band == 127) accum_q<0, 2>(xb, w9, gy, lane, acc);
    else                  accum_q<0, 3>(xb, w9, gy, lane, acc);

    #pragma unroll
    for (int o = 0; o < 2; ++o)
        #pragma unroll
        for (int k = 0; k < 4; ++k)
            sred[which][chunk][o][k][lane] = acc[o][k];
    __syncthreads();

    // f for 1024 (which,row,px) cells: 2 per thread, into registers first.
    double fv0, fv1;
    {
        int idx = tid;                       // it = 0
        int wh = idx >> 9, row = (idx >> 8) & 1, px = idx & 255;
        int k = px & 3, l = px >> 2;
        double s = sred[wh][0][row][k][l] + sred[wh][1][row][k][l]
                 + sred[wh][2][row][k][l] + sred[wh][3][row][k][l] + bias[wh];
        fv0 = 1.0 + 1.0 / (1.0 + exp(-s));
    }
    {
        int idx = 512 + tid;                 // it = 1
        int wh = idx >> 9, row = (idx >> 8) & 1, px = idx & 255;
        int k = px & 3, l = px >> 2;
        double s = sred[wh][0][row][k][l] + sred[wh][1][row][k][l]
                 + sred[wh][2][row][k][l] + sred[wh][3][row][k][l] + bias[wh];
        fv1 = 1.0 + 1.0 / (1.0 + exp(-s));
    }
    __syncthreads();                         // all sred reads done

    double* sf = &sred[0][0][0][0][0];       // reuse as flat [which*512 + row*256 + px]
    sf[tid] = fv0;
    sf[512 + tid] = fv1;
    __syncthreads();

    // ---- select phase: 2 rows x 64 ch, reading L2-hot x, writing out ----
    const int tx = tid & 63;                 // float4 column
    const int tc = tid >> 6;                 // 0..7 channel group

    double g0[2][4], g1[2][4];               // [row][j]
    #pragma unroll
    for (int row = 0; row < 2; ++row)
        #pragma unroll
        for (int j = 0; j < 4; ++j) {
            g0[row][j] = sf[row * 256 + tx * 4 + j];
            g1[row][j] = sf[512 + row * 256 + tx * 4 + j];
        }

    unsigned int cnt = 0;
    const size_t base = (size_t)b * C * PSZ + (size_t)y0 * W + (size_t)tx * 4;
    #pragma unroll 1
    for (int ci = tc; ci < C; ci += 8) {
        #pragma unroll
        for (int row = 0; row < 2; ++row) {
            size_t off = base + (size_t)ci * PSZ + (size_t)row * W;
            float4 a  = *(const float4*)(x0 + off);
            float4 bb = *(const float4*)(x1 + off);
            float4 r;
            { double v0=(double)a.x*g0[row][0], v1=(double)bb.x*g1[row][0]; bool s1=(v1>v0); cnt+=s1; r.x=s1?bb.x:a.x; }
            { double v0=(double)a.y*g0[row][1], v1=(double)bb.y*g1[row][1]; bool s1=(v1>v0); cnt+=s1; r.y=s1?bb.y:a.y; }
            { double v0=(double)a.z*g0[row][2], v1=(double)bb.z*g1[row][2]; bool s1=(v1>v0); cnt+=s1; r.z=s1?bb.z:a.z; }
            { double v0=(double)a.w*g0[row][3], v1=(double)bb.w*g1[row][3]; bool s1=(v1>v0); cnt+=s1; r.w=s1?bb.w:a.w; }
            *(float4*)(out + off) = r;
        }
    }

    atomicAdd(&scnt, cnt);
    __syncthreads();
    if (tid == 0) atomicAdd(count1, scnt);
}

__global__ void finalize_kernel(const unsigned int* __restrict__ count1,
                                float* __restrict__ out_p)
{
    const double N = (double)B * C * H * W;
    double c1 = (double)(*count1);
    out_p[0] = (float)((N - c1) / N);
    out_p[1] = (float)(c1 / N);
}

extern "C" void kernel_launch(void* const* d_in, const int* in_sizes, int n_in,
                              void* d_out, int out_size, void* d_ws, size_t ws_size,
                              hipStream_t stream) {
    const float* x0    = (const float*)d_in[0];
    const float* x1    = (const float*)d_in[1];
    const float* dw_w0 = (const float*)d_in[2];
    const float* dw_b0 = (const float*)d_in[3];
    const float* pw_w0 = (const float*)d_in[4];
    const float* pw_b0 = (const float*)d_in[5];
    const float* dw_w1 = (const float*)d_in[6];
    const float* dw_b1 = (const float*)d_in[7];
    const float* pw_w1 = (const float*)d_in[8];
    const float* pw_b1 = (const float*)d_in[9];
    float* out = (float*)d_out;

    unsigned int* cnt  = (unsigned int*)d_ws;
    double*       wc   = (double*)((char*)d_ws + OFF_WC);
    double*       bias = (double*)((char*)d_ws + OFF_BIAS);

    (void)hipMemsetAsync(d_ws, 0, 256, stream);

    prep_kernel<<<1, 128, 0, stream>>>(dw_w0, dw_b0, pw_w0, pw_b0,
                                       dw_w1, dw_b1, pw_w1, pw_b1, wc, bias);

    fused_kernel<<<B * (H / 2), 512, 0, stream>>>(x0, x1, wc, bias, out, cnt);

    finalize_kernel<<<1, 1, 0, stream>>>(cnt, out + (size_t)B * C * H * W);
}